// Round 5
// baseline (237.141 us; speedup 1.0000x reference)
//
#include <hip/hip_runtime.h>
#include <hip/hip_bf16.h>

// Conv2DAttentionBlock: B=16, C=128, HW=1024, 4 heads x d=128 attention + 1x1 convs.
// All GEMM-shaped stages in bf16 MFMA (16x16x32), fp32 accumulate.
// Workspace layout (needs 71,827,456 bytes):
//   wqkv  bf16[1536][128]           @ 0           (Wq rows pre-scaled by 1/sqrt(128)*log2e)
//   wtb   bf16[128][512]            @ 393216
//   xt    bf16[16][1024][128]       @ 524288      (x transposed, n-major)
//   Qt    bf16[16][4][1024][128]    @ 4718592     (n-major, pre-scaled)
//   Kt    bf16[16][4][1024][128]    @ 21495808    (m-major)
//   Vd    bf16[16][4][128][1024]    @ 38273024    (d-major)
//   Oscr  bf16[16][1024][512]       @ 55050240    (scrambled-transposed attn out)

#define NB 16
#define CD 128
#define HWN 1024
#define NH 4
#define KVB 64

typedef __attribute__((ext_vector_type(8))) short bf16x8;
typedef __attribute__((ext_vector_type(4))) short bf16x4;
typedef __attribute__((ext_vector_type(4))) float f32x4;

static __device__ __forceinline__ short f2bf(float f) {
  union { float f; unsigned u; } v; v.f = f;
  unsigned r = v.u + 0x7fffu + ((v.u >> 16) & 1u);  // RNE
  return (short)(r >> 16);
}

// ---- weights: fp32 -> bf16 (Wq scaled by softmax scale in log2 domain) --
__global__ void cvt_weights(const float* __restrict__ Wq, const float* __restrict__ Wk,
                            const float* __restrict__ Wv, const float* __restrict__ Wt,
                            short* __restrict__ wqkv, short* __restrict__ wtb) {
  const float SC = 0.08838834764831845f * 1.44269504088896341f;  // 1/sqrt(128)*log2(e)
  int i = blockIdx.x * 256 + threadIdx.x;  // grid covers exactly 65536
  wqkv[i]          = f2bf(Wq[i] * SC);
  wqkv[i + 65536]  = f2bf(Wk[i]);
  wqkv[i + 131072] = f2bf(Wv[i]);
  wtb[i]           = f2bf(Wt[i]);
}

// ---- x[b][c][n] fp32 -> xt[b][n][c] bf16 (LDS tile transpose) -----------
__global__ void cvt_transpose_x(const float* __restrict__ x, short* __restrict__ xt) {
  __shared__ short tile[32][33];
  int b = blockIdx.z, c0 = blockIdx.y * 32, n0 = blockIdx.x * 32;
  int tx = threadIdx.x & 31, ty = threadIdx.x >> 5;  // 32x8
  const float* xp = x + ((size_t)b * CD + c0) * HWN + n0;
  for (int k = 0; k < 4; ++k)
    tile[ty + 8 * k][tx] = f2bf(xp[(size_t)(ty + 8 * k) * HWN + tx]);
  __syncthreads();
  short* xo = xt + ((size_t)b * HWN + n0) * CD + c0;
  for (int k = 0; k < 4; ++k)
    xo[(size_t)(ty + 8 * k) * CD + tx] = tile[tx][ty + 8 * k];
}

// ---- QKV: Y[o][n] = sum_c Wqkv[o][c] * x[c][n]; scatter to Qt/Kt/Vd -----
__launch_bounds__(256)
__global__ void qkv_gemm(const short* __restrict__ wqkv, const short* __restrict__ xt,
                         const float* __restrict__ bv,
                         short* __restrict__ Qt, short* __restrict__ Kt,
                         short* __restrict__ Vd) {
  int b = blockIdx.z;
  int wave = threadIdx.x >> 6, lane = threadIdx.x & 63;
  int l15 = lane & 15, l4 = lane >> 4;
  int o0 = blockIdx.y * 64 + wave * 16;   // gridDim.y = 24
  int n0 = blockIdx.x * 128;              // gridDim.x = 8

  bf16x8 afrag[4];
  for (int kt = 0; kt < 4; ++kt)
    afrag[kt] = *(const bf16x8*)(wqkv + (size_t)(o0 + l15) * CD + kt * 32 + l4 * 8);

  f32x4 acc[8];
  for (int jt = 0; jt < 8; ++jt) acc[jt] = (f32x4){0.f, 0.f, 0.f, 0.f};

  const short* xb = xt + (size_t)b * HWN * CD;
  for (int jt = 0; jt < 8; ++jt) {
    int n = n0 + jt * 16 + l15;
    for (int kt = 0; kt < 4; ++kt) {
      bf16x8 bfrag = *(const bf16x8*)(xb + (size_t)n * CD + kt * 32 + l4 * 8);
      acc[jt] = __builtin_amdgcn_mfma_f32_16x16x32_bf16(afrag[kt], bfrag, acc[jt], 0, 0, 0);
    }
  }

  if (o0 < 1024) {  // Q or K -> [b][h][n][d]
    short* dst = (o0 < 512) ? Qt : Kt;
    int oo = (o0 < 512) ? o0 : o0 - 512;
    int h = oo >> 7, d0 = (oo & 127) + l4 * 4;
    for (int jt = 0; jt < 8; ++jt) {
      int n = n0 + jt * 16 + l15;
      bf16x4 v4;
      for (int r = 0; r < 4; ++r) v4[r] = f2bf(acc[jt][r]);
      *(bf16x4*)(dst + (((size_t)b * NH + h) * HWN + n) * CD + d0) = v4;
    }
  } else {          // V -> [b][h][d][m] (+bv), scattered 2B stores
    int oo = o0 - 1024;
    int h = oo >> 7, d0 = (oo & 127) + l4 * 4;
    float bvv[4];
    for (int r = 0; r < 4; ++r) bvv[r] = bv[oo + l4 * 4 + r];
    for (int jt = 0; jt < 8; ++jt) {
      int n = n0 + jt * 16 + l15;
      for (int r = 0; r < 4; ++r)
        Vd[(((size_t)b * NH + h) * CD + d0 + r) * HWN + n] = f2bf(acc[jt][r] + bvv[r]);
    }
  }
}

// ---- flash attention per (b,h): S=1024, D=128 ---------------------------
// 4 waves/block, wave owns 16 Q-rows. Grid 1024 (XCD chunk-swizzled; all 16
// blocks of a (b,h) on one XCD's L2) -> 4 independent blocks/CU = 4
// waves/SIMD from different blocks (latency hiding despite intra-block
// barrier). K staged block-cooperatively in LDS (double-buffered
// global_load_lds width=16, XOR-swizzled via pre-swizzled global source).
// V direct from global (L2-resident), half-tile at a time. Swapped QK^T ->
// in-register softmax (log2 domain, Q pre-scaled), defer-max. P via
// per-wave LDS subtiles. setprio(1) around MFMA clusters.
__launch_bounds__(256, 4)
__global__ void attn(const short* __restrict__ Qt, const short* __restrict__ Kt,
                     const short* __restrict__ Vd, short* __restrict__ Oscr) {
  // XCD chunk swizzle: nwg=1024, 8 XCDs, 128 blocks per XCD chunk (bijective).
  int wid = blockIdx.x;
  int work = (wid & 7) * 128 + (wid >> 3);
  int xb = work & 15;
  int h = (work >> 4) & 3;
  int b = work >> 6;

  int wave = threadIdx.x >> 6, lane = threadIdx.x & 63;
  int l15 = lane & 15, l4 = lane >> 4;
  int n0 = xb * 64 + wave * 16;
  size_t bh = (size_t)b * NH + h;
  const short* q = Qt + bh * HWN * CD;
  const short* k = Kt + bh * HWN * CD;
  const short* v = Vd + bh * CD * HWN;

  __shared__ short Kls[2][KVB * CD];    // 32 KB, rows XOR-swizzled (byte^=(row&7)<<4)
  __shared__ short pl[4][2][4][16][8];  // [wave][ks][g][n][e] 8 KB

  // stage K tile (64x128 bf16 = 16KB) into Kls[buf]; 16 x 1KB insts over 4 waves.
  // LDS dest linear; global source pre-swizzled so LDS holds K[row][col^((row&7)<<4 bytes)].
#define STAGE(buf, m0s)                                                       \
  for (int j = 0; j < 4; ++j) {                                               \
    int ii = wave * 4 + j;                                                    \
    int row = ii * 4 + l4;                                                    \
    int scol = (l15 * 16) ^ ((row & 7) << 4);                                 \
    const short* gp = k + (size_t)((m0s) + row) * CD + (scol >> 1);           \
    __builtin_amdgcn_global_load_lds(                                         \
        (const __attribute__((address_space(1))) void*)gp,                    \
        (__attribute__((address_space(3))) void*)&Kls[buf][ii * 512],         \
        16, 0, 0);                                                            \
  }

  bf16x8 bq[4];  // Q as B-fragment (col = n = l15, k = c), pre-scaled
  for (int kt = 0; kt < 4; ++kt)
    bq[kt] = *(const bf16x8*)(q + (size_t)(n0 + l15) * CD + kt * 32 + l4 * 8);

  f32x4 oacc[8];
  for (int jt = 0; jt < 8; ++jt) oacc[jt] = (f32x4){0.f, 0.f, 0.f, 0.f};
  float mi = -1e30f, li = 0.f;

  STAGE(0, 0)
  __syncthreads();

  for (int mt = 0; mt < 16; ++mt) {
    int m0 = mt * KVB;
    int cur = mt & 1;
    if (mt < 15) STAGE(cur ^ 1, m0 + KVB)

    // QK^T swapped: s[t] = S^T[m0+16t+4*l4+r][n0+l15]; K from LDS (swizzled read)
    f32x4 s[4];
    for (int t = 0; t < 4; ++t) s[t] = (f32x4){0.f, 0.f, 0.f, 0.f};
    __builtin_amdgcn_s_setprio(1);
#pragma unroll
    for (int t = 0; t < 4; ++t) {
      int row = t * 16 + l15;
#pragma unroll
      for (int kt = 0; kt < 4; ++kt) {
        bf16x8 ak = *(const bf16x8*)&Kls[cur][row * CD + ((kt * 32 + l4 * 8) ^ ((l15 & 7) << 3))];
        s[t] = __builtin_amdgcn_mfma_f32_16x16x32_bf16(ak, bq[kt], s[t], 0, 0, 0);
      }
    }
    __builtin_amdgcn_s_setprio(0);

    // V half-0 loads issued now; consumed after softmax (latency hidden)
    bf16x8 vf[8];
#pragma unroll
    for (int jt = 0; jt < 8; ++jt)
      vf[jt] = *(const bf16x8*)(v + (size_t)(jt * 16 + l15) * HWN + m0 + l4 * 8);

    // softmax stats: lane holds 16 of 64 m-values for q-row n = n0+l15 (log2 domain)
    float mx = -1e30f;
    for (int t = 0; t < 4; ++t)
      for (int r = 0; r < 4; ++r) mx = fmaxf(mx, s[t][r]);
    mx = fmaxf(mx, __shfl_xor(mx, 16));
    mx = fmaxf(mx, __shfl_xor(mx, 32));
    if (!__all(mx - mi <= 8.0f)) {
      float nm = fmaxf(mi, mx);
      float fac = __builtin_amdgcn_exp2f(mi - nm);
      mi = nm;
      li *= fac;
      float facb[4];
      for (int r = 0; r < 4; ++r)
        facb[r] = __shfl(fac, (lane & 48) | (l4 * 4 + r));
      for (int jt = 0; jt < 8; ++jt)
        for (int r = 0; r < 4; ++r) oacc[jt][r] *= facb[r];
    }
    float ls = 0.f;
    float p[4][4];
    for (int t = 0; t < 4; ++t)
      for (int r = 0; r < 4; ++r) {
        float e = __builtin_amdgcn_exp2f(s[t][r] - mi);
        p[t][r] = e;
        ls += e;
      }
    ls += __shfl_xor(ls, 16);
    ls += __shfl_xor(ls, 32);
    li += ls;

    // P -> per-wave LDS subtiles, read back as A fragments
    for (int t = 0; t < 4; ++t) {
      bf16x4 c4;
      for (int r = 0; r < 4; ++r) c4[r] = f2bf(p[t][r]);
      *(bf16x4*)&pl[wave][t >> 1][2 * (t & 1) + (l4 >> 1)][l15][4 * (l4 & 1)] = c4;
    }
    bf16x8 ap0 = *(const bf16x8*)&pl[wave][0][l4][l15][0];
    bf16x8 ap1 = *(const bf16x8*)&pl[wave][1][l4][l15][0];

    // PV half-0 (V ks=0 already in flight)
    __builtin_amdgcn_s_setprio(1);
#pragma unroll
    for (int jt = 0; jt < 8; ++jt)
      oacc[jt] = __builtin_amdgcn_mfma_f32_16x16x32_bf16(ap0, vf[jt], oacc[jt], 0, 0, 0);
    __builtin_amdgcn_s_setprio(0);

    // V half-1 into the same regs (WAR renamed by allocator where possible)
#pragma unroll
    for (int jt = 0; jt < 8; ++jt)
      vf[jt] = *(const bf16x8*)(v + (size_t)(jt * 16 + l15) * HWN + m0 + 32 + l4 * 8);
    __builtin_amdgcn_s_setprio(1);
#pragma unroll
    for (int jt = 0; jt < 8; ++jt)
      oacc[jt] = __builtin_amdgcn_mfma_f32_16x16x32_bf16(ap1, vf[jt], oacc[jt], 0, 0, 0);
    __builtin_amdgcn_s_setprio(0);

    __syncthreads();  // staging for mt+1 complete; all waves done with Kls[cur]
  }
#undef STAGE

  // epilogue: O[n][d]/l -> Oscr[b][m=(n%8)*128+d][o=h*128+n/8]  (bijective)
  float inv = 1.0f / li;  // for row n = n0+l15, replicated over l4
  float invb[4];
  for (int r = 0; r < 4; ++r)
    invb[r] = __shfl(inv, (lane & 48) | (l4 * 4 + r));
  for (int jt = 0; jt < 8; ++jt) {
    int d = jt * 16 + l15;
    for (int r = 0; r < 4; ++r) {
      int n = n0 + l4 * 4 + r;
      int o = h * CD + (n >> 3);
      int msp = (n & 7) * CD + d;
      Oscr[((size_t)b * HWN + msp) * 512 + o] = f2bf(oacc[jt][r] * invb[r]);
    }
  }
}

// ---- proj: out[b][c][m] = x + bt[c] + sum_o Wt[c][o]*OscrT[m][o] --------
__launch_bounds__(256)
__global__ void proj_kernel(const short* __restrict__ Oscr, const short* __restrict__ wtb,
                            const float* __restrict__ bt, const float* __restrict__ x,
                            float* __restrict__ out) {
  int b = blockIdx.y;
  int wave = threadIdx.x >> 6, lane = threadIdx.x & 63;
  int l15 = lane & 15, l4 = lane >> 4;
  int m0 = blockIdx.x * 64 + wave * 16;   // gridDim.x = 16

  f32x4 acc[8];
  for (int jt = 0; jt < 8; ++jt) acc[jt] = (f32x4){0.f, 0.f, 0.f, 0.f};

  const short* ob = Oscr + (size_t)b * HWN * 512;
  for (int kt = 0; kt < 16; ++kt) {
    bf16x8 a = *(const bf16x8*)(ob + (size_t)(m0 + l15) * 512 + kt * 32 + l4 * 8);
    for (int jt = 0; jt < 8; ++jt) {
      bf16x8 bw = *(const bf16x8*)(wtb + (size_t)(jt * 16 + l15) * 512 + kt * 32 + l4 * 8);
      acc[jt] = __builtin_amdgcn_mfma_f32_16x16x32_bf16(a, bw, acc[jt], 0, 0, 0);
    }
  }
  for (int jt = 0; jt < 8; ++jt) {
    int c = jt * 16 + l15;
    float btc = bt[c];
    size_t base = ((size_t)b * CD + c) * HWN + m0 + l4 * 4;
    f32x4 xr = *(const f32x4*)(x + base);
    f32x4 o;
    for (int r = 0; r < 4; ++r) o[r] = acc[jt][r] + xr[r] + btc;
    *(f32x4*)(out + base) = o;
  }
}

extern "C" void kernel_launch(void* const* d_in, const int* in_sizes, int n_in,
                              void* d_out, int out_size, void* d_ws, size_t ws_size,
                              hipStream_t stream) {
  const float* x  = (const float*)d_in[0];
  const float* Wq = (const float*)d_in[1];
  const float* Wk = (const float*)d_in[2];
  const float* Wv = (const float*)d_in[3];
  const float* bv = (const float*)d_in[4];
  const float* Wt = (const float*)d_in[5];
  const float* bt = (const float*)d_in[6];
  float* out = (float*)d_out;
  char* ws = (char*)d_ws;

  short* wqkv = (short*)(ws);
  short* wtb  = (short*)(ws + 393216);
  short* xt   = (short*)(ws + 524288);
  short* Qt   = (short*)(ws + 4718592);
  short* Kt   = (short*)(ws + 21495808);
  short* Vd   = (short*)(ws + 38273024);
  short* Oscr = (short*)(ws + 55050240);  // total 71827456 bytes

  hipLaunchKernelGGL(cvt_weights, dim3(256), dim3(256), 0, stream, Wq, Wk, Wv, Wt, wqkv, wtb);
  hipLaunchKernelGGL(cvt_transpose_x, dim3(32, 4, 16), dim3(256), 0, stream, x, xt);
  hipLaunchKernelGGL(qkv_gemm, dim3(8, 24, 16), dim3(256), 0, stream, wqkv, xt, bv, Qt, Kt, Vd);
  hipLaunchKernelGGL(attn, dim3(1024), dim3(256), 0, stream, Qt, Kt, Vd, Oscr);
  hipLaunchKernelGGL(proj_kernel, dim3(16, 16), dim3(256), 0, stream, Oscr, wtb, bt, x, out);
}

// Round 6
// 234.149 us; speedup vs baseline: 1.0128x; 1.0128x over previous
//
#include <hip/hip_runtime.h>
#include <hip/hip_bf16.h>

// Conv2DAttentionBlock: B=16, C=128, HW=1024, 4 heads x d=128 attention + 1x1 convs.
// All GEMM-shaped stages in bf16 MFMA (16x16x32), fp32 accumulate.
// Workspace layout (needs 71,827,456 bytes):
//   wqkv  bf16[1536][128]           @ 0           (Wq rows pre-scaled by 1/sqrt(128)*log2e)
//   wtb   bf16[128][512]            @ 393216
//   xt    bf16[16][1024][128]       @ 524288      (x transposed, n-major)
//   Qt    bf16[16][4][1024][128]    @ 4718592     (n-major, pre-scaled)
//   Kt    bf16[16][4][1024][128]    @ 21495808    (m-major)
//   Vd    bf16[16][4][128][1024]    @ 38273024    (d-major)
//   Oscr  bf16[16][1024][512]       @ 55050240    (scrambled-transposed attn out)

#define NB 16
#define CD 128
#define HWN 1024
#define NH 4
#define KVB 128

typedef __attribute__((ext_vector_type(8))) short bf16x8;
typedef __attribute__((ext_vector_type(4))) short bf16x4;
typedef __attribute__((ext_vector_type(4))) float f32x4;

static __device__ __forceinline__ short f2bf(float f) {
  union { float f; unsigned u; } v; v.f = f;
  unsigned r = v.u + 0x7fffu + ((v.u >> 16) & 1u);  // RNE
  return (short)(r >> 16);
}

// ---- weights: fp32 -> bf16 (Wq scaled by softmax scale in log2 domain) --
__global__ void cvt_weights(const float* __restrict__ Wq, const float* __restrict__ Wk,
                            const float* __restrict__ Wv, const float* __restrict__ Wt,
                            short* __restrict__ wqkv, short* __restrict__ wtb) {
  const float SC = 0.08838834764831845f * 1.44269504088896341f;  // 1/sqrt(128)*log2(e)
  int i = blockIdx.x * 256 + threadIdx.x;  // grid covers exactly 65536
  wqkv[i]          = f2bf(Wq[i] * SC);
  wqkv[i + 65536]  = f2bf(Wk[i]);
  wqkv[i + 131072] = f2bf(Wv[i]);
  wtb[i]           = f2bf(Wt[i]);
}

// ---- x[b][c][n] fp32 -> xt[b][n][c] bf16 (LDS tile transpose) -----------
__global__ void cvt_transpose_x(const float* __restrict__ x, short* __restrict__ xt) {
  __shared__ short tile[32][33];
  int b = blockIdx.z, c0 = blockIdx.y * 32, n0 = blockIdx.x * 32;
  int tx = threadIdx.x & 31, ty = threadIdx.x >> 5;  // 32x8
  const float* xp = x + ((size_t)b * CD + c0) * HWN + n0;
  for (int k = 0; k < 4; ++k)
    tile[ty + 8 * k][tx] = f2bf(xp[(size_t)(ty + 8 * k) * HWN + tx]);
  __syncthreads();
  short* xo = xt + ((size_t)b * HWN + n0) * CD + c0;
  for (int k = 0; k < 4; ++k)
    xo[(size_t)(ty + 8 * k) * CD + tx] = tile[tx][ty + 8 * k];
}

// ---- QKV: Y[o][n] = sum_c Wqkv[o][c] * x[c][n]; scatter to Qt/Kt/Vd -----
__launch_bounds__(256)
__global__ void qkv_gemm(const short* __restrict__ wqkv, const short* __restrict__ xt,
                         const float* __restrict__ bv,
                         short* __restrict__ Qt, short* __restrict__ Kt,
                         short* __restrict__ Vd) {
  int b = blockIdx.z;
  int wave = threadIdx.x >> 6, lane = threadIdx.x & 63;
  int l15 = lane & 15, l4 = lane >> 4;
  int o0 = blockIdx.y * 64 + wave * 16;   // gridDim.y = 24
  int n0 = blockIdx.x * 128;              // gridDim.x = 8

  bf16x8 afrag[4];
  for (int kt = 0; kt < 4; ++kt)
    afrag[kt] = *(const bf16x8*)(wqkv + (size_t)(o0 + l15) * CD + kt * 32 + l4 * 8);

  f32x4 acc[8];
  for (int jt = 0; jt < 8; ++jt) acc[jt] = (f32x4){0.f, 0.f, 0.f, 0.f};

  const short* xb = xt + (size_t)b * HWN * CD;
  for (int jt = 0; jt < 8; ++jt) {
    int n = n0 + jt * 16 + l15;
    for (int kt = 0; kt < 4; ++kt) {
      bf16x8 bfrag = *(const bf16x8*)(xb + (size_t)n * CD + kt * 32 + l4 * 8);
      acc[jt] = __builtin_amdgcn_mfma_f32_16x16x32_bf16(afrag[kt], bfrag, acc[jt], 0, 0, 0);
    }
  }

  if (o0 < 1024) {  // Q or K -> [b][h][n][d]
    short* dst = (o0 < 512) ? Qt : Kt;
    int oo = (o0 < 512) ? o0 : o0 - 512;
    int h = oo >> 7, d0 = (oo & 127) + l4 * 4;
    for (int jt = 0; jt < 8; ++jt) {
      int n = n0 + jt * 16 + l15;
      bf16x4 v4;
      for (int r = 0; r < 4; ++r) v4[r] = f2bf(acc[jt][r]);
      *(bf16x4*)(dst + (((size_t)b * NH + h) * HWN + n) * CD + d0) = v4;
    }
  } else {          // V -> [b][h][d][m] (+bv), scattered 2B stores
    int oo = o0 - 1024;
    int h = oo >> 7, d0 = (oo & 127) + l4 * 4;
    float bvv[4];
    for (int r = 0; r < 4; ++r) bvv[r] = bv[oo + l4 * 4 + r];
    for (int jt = 0; jt < 8; ++jt) {
      int n = n0 + jt * 16 + l15;
      for (int r = 0; r < 4; ++r)
        Vd[(((size_t)b * NH + h) * CD + d0 + r) * HWN + n] = f2bf(acc[jt][r] + bvv[r]);
    }
  }
}

// ---- flash attention per (b,h): S=1024, D=128 ---------------------------
// 4 waves/block, wave owns 32 Q-rows (2 fragments). K-tile = 128 rows ->
// only 8 barrier intervals, 128 MFMAs/wave/interval (overhead amortized).
// Grid 512, XCD chunk-swizzled (all 8 blocks of a (b,h) on one XCD's L2).
// K staged block-cooperatively in LDS (double-buffered global_load_lds
// width=16, XOR-swizzled via pre-swizzled global source). V direct from
// global in 4 m-chunks with 2-deep reg double-buffer (issue-early).
// Swapped QK^T -> in-register softmax (log2 domain, Q pre-scaled),
// defer-max. P staged via reused 8KB LDS chunk (intra-wave DS ordering).
// launch_bounds(256,2): 256-reg budget, no spills.
__launch_bounds__(256, 2)
__global__ void attn(const short* __restrict__ Qt, const short* __restrict__ Kt,
                     const short* __restrict__ Vd, short* __restrict__ Oscr) {
  // XCD chunk swizzle: nwg=512, 8 XCDs, 64 blocks per XCD chunk (bijective).
  int wid = blockIdx.x;
  int work = (wid & 7) * 64 + (wid >> 3);
  int xb = work & 7;          // q-block of 128 rows
  int h = (work >> 3) & 3;
  int b = work >> 5;

  int wave = threadIdx.x >> 6, lane = threadIdx.x & 63;
  int l15 = lane & 15, l4 = lane >> 4;
  int n0 = xb * 128 + wave * 32;
  size_t bh = (size_t)b * NH + h;
  const short* q = Qt + bh * HWN * CD;
  const short* k = Kt + bh * HWN * CD;
  const short* v = Vd + bh * CD * HWN;

  __shared__ short Kls[2][KVB * CD];    // 2 x 32 KB, rows XOR-swizzled (byte^=(row&7)<<4)
  __shared__ short pl[4][2][4][16][8];  // [wave][qf][g][n][e] 8 KB, reused per m-chunk

  // stage K tile (128x128 bf16 = 32KB) into Kls[buf]; 32 x 1KB insts over 4 waves.
  // LDS dest linear; global source pre-swizzled so LDS holds K[row][col^((row&7)<<4 bytes)].
#define STAGE(buf, m0s)                                                       \
  for (int j = 0; j < 8; ++j) {                                               \
    int ii = wave * 8 + j;                                                    \
    int row = ii * 4 + l4;                                                    \
    int scol = (l15 * 16) ^ ((row & 7) << 4);                                 \
    const short* gp = k + (size_t)((m0s) + row) * CD + (scol >> 1);           \
    __builtin_amdgcn_global_load_lds(                                         \
        (const __attribute__((address_space(1))) void*)gp,                    \
        (__attribute__((address_space(3))) void*)&Kls[buf][ii * 512],         \
        16, 0, 0);                                                            \
  }

  // P chunk write (both qf) for sub-tiles t=2*KS, 2*KS+1; then A-frag reads.
#define PWRITE(KS)                                                            \
  for (int qf = 0; qf < 2; ++qf)                                              \
    for (int dt = 0; dt < 2; ++dt) {                                          \
      bf16x4 c4;                                                              \
      for (int r = 0; r < 4; ++r) c4[r] = f2bf(s[qf][2 * (KS) + dt][r]);      \
      *(bf16x4*)&pl[wave][qf][2 * dt + (l4 >> 1)][l15][4 * (l4 & 1)] = c4;    \
    }
#define PREAD(a0, a1)                                                         \
  a0 = *(const bf16x8*)&pl[wave][0][l4][l15][0];                              \
  a1 = *(const bf16x8*)&pl[wave][1][l4][l15][0];
#define VLOAD(dst, KS)                                                        \
  for (int jt = 0; jt < 8; ++jt)                                              \
    dst[jt] = *(const bf16x8*)(v + (size_t)(jt * 16 + l15) * HWN + m0 +       \
                               (KS) * 32 + l4 * 8);
#define PVMFMA(a0, a1, vf)                                                    \
  __builtin_amdgcn_s_setprio(1);                                              \
  for (int jt = 0; jt < 8; ++jt) {                                            \
    oacc[0][jt] = __builtin_amdgcn_mfma_f32_16x16x32_bf16(a0, vf[jt], oacc[0][jt], 0, 0, 0); \
    oacc[1][jt] = __builtin_amdgcn_mfma_f32_16x16x32_bf16(a1, vf[jt], oacc[1][jt], 0, 0, 0); \
  }                                                                           \
  __builtin_amdgcn_s_setprio(0);

  bf16x8 bq[2][4];  // Q as B-fragment (col = n, k = c), pre-scaled
  for (int qf = 0; qf < 2; ++qf)
    for (int kt = 0; kt < 4; ++kt)
      bq[qf][kt] = *(const bf16x8*)(q + (size_t)(n0 + qf * 16 + l15) * CD + kt * 32 + l4 * 8);

  f32x4 oacc[2][8];
  for (int qf = 0; qf < 2; ++qf)
    for (int jt = 0; jt < 8; ++jt) oacc[qf][jt] = (f32x4){0.f, 0.f, 0.f, 0.f};
  float mi[2] = {-1e30f, -1e30f}, li[2] = {0.f, 0.f};

  STAGE(0, 0)
  __syncthreads();

  for (int mt = 0; mt < 8; ++mt) {
    int m0 = mt * KVB;
    int cur = mt & 1;
    if (mt < 7) STAGE(cur ^ 1, m0 + KVB)

    // QK^T swapped: s[qf][t] = S^T[m0+16t+4*l4+r][n0+16qf+l15]; K from LDS
    f32x4 s[2][8];
    for (int qf = 0; qf < 2; ++qf)
      for (int t = 0; t < 8; ++t) s[qf][t] = (f32x4){0.f, 0.f, 0.f, 0.f};
    __builtin_amdgcn_s_setprio(1);
#pragma unroll
    for (int t = 0; t < 8; ++t) {
      int row = t * 16 + l15;
#pragma unroll
      for (int kt = 0; kt < 4; ++kt) {
        bf16x8 ak = *(const bf16x8*)&Kls[cur][row * CD + ((kt * 32 + l4 * 8) ^ ((l15 & 7) << 3))];
        s[0][t] = __builtin_amdgcn_mfma_f32_16x16x32_bf16(ak, bq[0][kt], s[0][t], 0, 0, 0);
        s[1][t] = __builtin_amdgcn_mfma_f32_16x16x32_bf16(ak, bq[1][kt], s[1][t], 0, 0, 0);
      }
    }
    __builtin_amdgcn_s_setprio(0);

    // V chunks 0,1 issued now; consumed after softmax (latency hidden)
    bf16x8 vfA[8], vfB[8];
    VLOAD(vfA, 0)
    VLOAD(vfB, 1)

    // softmax stats over 128 m-values: lane holds 32 per qf (log2 domain)
    float mx[2];
    for (int qf = 0; qf < 2; ++qf) {
      float m2 = -1e30f;
      for (int t = 0; t < 8; ++t)
        for (int r = 0; r < 4; ++r) m2 = fmaxf(m2, s[qf][t][r]);
      m2 = fmaxf(m2, __shfl_xor(m2, 16));
      m2 = fmaxf(m2, __shfl_xor(m2, 32));
      mx[qf] = m2;
    }
    if (!__all((mx[0] - mi[0] <= 8.0f) && (mx[1] - mi[1] <= 8.0f))) {
      for (int qf = 0; qf < 2; ++qf) {
        float nm = fmaxf(mi[qf], mx[qf]);
        float fac = __builtin_amdgcn_exp2f(mi[qf] - nm);
        mi[qf] = nm;
        li[qf] *= fac;
        float facb[4];
        for (int r = 0; r < 4; ++r)
          facb[r] = __shfl(fac, (lane & 48) | (l4 * 4 + r));
        for (int jt = 0; jt < 8; ++jt)
          for (int r = 0; r < 4; ++r) oacc[qf][jt][r] *= facb[r];
      }
    }
    for (int qf = 0; qf < 2; ++qf) {
      float ls = 0.f;
      for (int t = 0; t < 8; ++t)
        for (int r = 0; r < 4; ++r) {
          float e = __builtin_amdgcn_exp2f(s[qf][t][r] - mi[qf]);
          s[qf][t][r] = e;  // P in place
          ls += e;
        }
      ls += __shfl_xor(ls, 16);
      ls += __shfl_xor(ls, 32);
      li[qf] += ls;
    }

    // PV in 4 m-chunks of 32, 2-deep pipeline (P via reused LDS chunk)
    bf16x8 apA0, apA1, apB0, apB1;
    PWRITE(0)
    PREAD(apA0, apA1)
    PWRITE(1)
    PREAD(apB0, apB1)
    PVMFMA(apA0, apA1, vfA)           // chunk 0
    PWRITE(2)
    PREAD(apA0, apA1)
    VLOAD(vfA, 2)
    PVMFMA(apB0, apB1, vfB)           // chunk 1
    PWRITE(3)
    PREAD(apB0, apB1)
    VLOAD(vfB, 3)
    PVMFMA(apA0, apA1, vfA)           // chunk 2
    PVMFMA(apB0, apB1, vfB)           // chunk 3

    __syncthreads();  // staging for mt+1 complete; all waves done with Kls[cur]
  }
#undef STAGE
#undef PWRITE
#undef PREAD
#undef VLOAD
#undef PVMFMA

  // epilogue: O[n][d]/l -> Oscr[b][m=(n%8)*128+d][o=h*128+n/8]  (bijective)
  for (int qf = 0; qf < 2; ++qf) {
    float inv = 1.0f / li[qf];  // for row n = n0+16qf+l15, replicated over l4
    float invb[4];
    for (int r = 0; r < 4; ++r)
      invb[r] = __shfl(inv, (lane & 48) | (l4 * 4 + r));
    for (int jt = 0; jt < 8; ++jt) {
      int d = jt * 16 + l15;
      for (int r = 0; r < 4; ++r) {
        int n = n0 + qf * 16 + l4 * 4 + r;
        int o = h * CD + (n >> 3);
        int msp = (n & 7) * CD + d;
        Oscr[((size_t)b * HWN + msp) * 512 + o] = f2bf(oacc[qf][jt][r] * invb[r]);
      }
    }
  }
}

// ---- proj: out[b][c][m] = x + bt[c] + sum_o Wt[c][o]*OscrT[m][o] --------
__launch_bounds__(256)
__global__ void proj_kernel(const short* __restrict__ Oscr, const short* __restrict__ wtb,
                            const float* __restrict__ bt, const float* __restrict__ x,
                            float* __restrict__ out) {
  int b = blockIdx.y;
  int wave = threadIdx.x >> 6, lane = threadIdx.x & 63;
  int l15 = lane & 15, l4 = lane >> 4;
  int m0 = blockIdx.x * 64 + wave * 16;   // gridDim.x = 16

  f32x4 acc[8];
  for (int jt = 0; jt < 8; ++jt) acc[jt] = (f32x4){0.f, 0.f, 0.f, 0.f};

  const short* ob = Oscr + (size_t)b * HWN * 512;
  for (int kt = 0; kt < 16; ++kt) {
    bf16x8 a = *(const bf16x8*)(ob + (size_t)(m0 + l15) * 512 + kt * 32 + l4 * 8);
    for (int jt = 0; jt < 8; ++jt) {
      bf16x8 bw = *(const bf16x8*)(wtb + (size_t)(jt * 16 + l15) * 512 + kt * 32 + l4 * 8);
      acc[jt] = __builtin_amdgcn_mfma_f32_16x16x32_bf16(a, bw, acc[jt], 0, 0, 0);
    }
  }
  for (int jt = 0; jt < 8; ++jt) {
    int c = jt * 16 + l15;
    float btc = bt[c];
    size_t base = ((size_t)b * CD + c) * HWN + m0 + l4 * 4;
    f32x4 xr = *(const f32x4*)(x + base);
    f32x4 o;
    for (int r = 0; r < 4; ++r) o[r] = acc[jt][r] + xr[r] + btc;
    *(f32x4*)(out + base) = o;
  }
}

extern "C" void kernel_launch(void* const* d_in, const int* in_sizes, int n_in,
                              void* d_out, int out_size, void* d_ws, size_t ws_size,
                              hipStream_t stream) {
  const float* x  = (const float*)d_in[0];
  const float* Wq = (const float*)d_in[1];
  const float* Wk = (const float*)d_in[2];
  const float* Wv = (const float*)d_in[3];
  const float* bv = (const float*)d_in[4];
  const float* Wt = (const float*)d_in[5];
  const float* bt = (const float*)d_in[6];
  float* out = (float*)d_out;
  char* ws = (char*)d_ws;

  short* wqkv = (short*)(ws);
  short* wtb  = (short*)(ws + 393216);
  short* xt   = (short*)(ws + 524288);
  short* Qt   = (short*)(ws + 4718592);
  short* Kt   = (short*)(ws + 21495808);
  short* Vd   = (short*)(ws + 38273024);
  short* Oscr = (short*)(ws + 55050240);  // total 71827456 bytes

  hipLaunchKernelGGL(cvt_weights, dim3(256), dim3(256), 0, stream, Wq, Wk, Wv, Wt, wqkv, wtb);
  hipLaunchKernelGGL(cvt_transpose_x, dim3(32, 4, 16), dim3(256), 0, stream, x, xt);
  hipLaunchKernelGGL(qkv_gemm, dim3(8, 24, 16), dim3(256), 0, stream, wqkv, xt, bv, Qt, Kt, Vd);
  hipLaunchKernelGGL(attn, dim3(512), dim3(256), 0, stream, Qt, Kt, Vd, Oscr);
  hipLaunchKernelGGL(proj_kernel, dim3(16, 16), dim3(256), 0, stream, Oscr, wtb, bt, x, out);
}

// Round 7
// 155.800 us; speedup vs baseline: 1.5221x; 1.5029x over previous
//
#include <hip/hip_runtime.h>
#include <hip/hip_bf16.h>

// Conv2DAttentionBlock: B=16, C=128, HW=1024, 4 heads x d=128 attention + 1x1 convs.
// All GEMM-shaped stages in bf16 MFMA (16x16x32), fp32 accumulate.
// Workspace layout (needs 71,827,456 bytes):
//   wqkv  bf16[1536][128]           @ 0           (Wq rows pre-scaled by 1/sqrt(128)*log2e)
//   wtb   bf16[128][512]            @ 393216
//   xt    bf16[16][1024][128]       @ 524288      (x transposed, n-major)
//   Qt    bf16[16][4][1024][128]    @ 4718592     (n-major, pre-scaled)
//   Kt    bf16[16][4][1024][128]    @ 21495808    (m-major)
//   Vd    bf16[16][4][128][1024]    @ 38273024    (d-major)
//   Oscr  bf16[16][1024][512]       @ 55050240    (scrambled-transposed attn out)

#define NB 16
#define CD 128
#define HWN 1024
#define NH 4
#define KVB 64

typedef __attribute__((ext_vector_type(8))) short bf16x8;
typedef __attribute__((ext_vector_type(4))) short bf16x4;
typedef __attribute__((ext_vector_type(4))) float f32x4;

static __device__ __forceinline__ short f2bf(float f) {
  union { float f; unsigned u; } v; v.f = f;
  unsigned r = v.u + 0x7fffu + ((v.u >> 16) & 1u);  // RNE
  return (short)(r >> 16);
}

// ---- weights: fp32 -> bf16 (Wq scaled by softmax scale in log2 domain) --
__global__ void cvt_weights(const float* __restrict__ Wq, const float* __restrict__ Wk,
                            const float* __restrict__ Wv, const float* __restrict__ Wt,
                            short* __restrict__ wqkv, short* __restrict__ wtb) {
  const float SC = 0.08838834764831845f * 1.44269504088896341f;  // 1/sqrt(128)*log2(e)
  int i = blockIdx.x * 256 + threadIdx.x;  // grid covers exactly 65536
  wqkv[i]          = f2bf(Wq[i] * SC);
  wqkv[i + 65536]  = f2bf(Wk[i]);
  wqkv[i + 131072] = f2bf(Wv[i]);
  wtb[i]           = f2bf(Wt[i]);
}

// ---- x[b][c][n] fp32 -> xt[b][n][c] bf16 (LDS tile transpose) -----------
__global__ void cvt_transpose_x(const float* __restrict__ x, short* __restrict__ xt) {
  __shared__ short tile[32][33];
  int b = blockIdx.z, c0 = blockIdx.y * 32, n0 = blockIdx.x * 32;
  int tx = threadIdx.x & 31, ty = threadIdx.x >> 5;  // 32x8
  const float* xp = x + ((size_t)b * CD + c0) * HWN + n0;
  for (int k = 0; k < 4; ++k)
    tile[ty + 8 * k][tx] = f2bf(xp[(size_t)(ty + 8 * k) * HWN + tx]);
  __syncthreads();
  short* xo = xt + ((size_t)b * HWN + n0) * CD + c0;
  for (int k = 0; k < 4; ++k)
    xo[(size_t)(ty + 8 * k) * CD + tx] = tile[tx][ty + 8 * k];
}

// ---- QKV: Y[o][n] = sum_c Wqkv[o][c] * x[c][n]; scatter to Qt/Kt/Vd -----
__launch_bounds__(256)
__global__ void qkv_gemm(const short* __restrict__ wqkv, const short* __restrict__ xt,
                         const float* __restrict__ bv,
                         short* __restrict__ Qt, short* __restrict__ Kt,
                         short* __restrict__ Vd) {
  int b = blockIdx.z;
  int wave = threadIdx.x >> 6, lane = threadIdx.x & 63;
  int l15 = lane & 15, l4 = lane >> 4;
  int o0 = blockIdx.y * 64 + wave * 16;   // gridDim.y = 24
  int n0 = blockIdx.x * 128;              // gridDim.x = 8

  bf16x8 afrag[4];
  for (int kt = 0; kt < 4; ++kt)
    afrag[kt] = *(const bf16x8*)(wqkv + (size_t)(o0 + l15) * CD + kt * 32 + l4 * 8);

  f32x4 acc[8];
  for (int jt = 0; jt < 8; ++jt) acc[jt] = (f32x4){0.f, 0.f, 0.f, 0.f};

  const short* xb = xt + (size_t)b * HWN * CD;
  for (int jt = 0; jt < 8; ++jt) {
    int n = n0 + jt * 16 + l15;
    for (int kt = 0; kt < 4; ++kt) {
      bf16x8 bfrag = *(const bf16x8*)(xb + (size_t)n * CD + kt * 32 + l4 * 8);
      acc[jt] = __builtin_amdgcn_mfma_f32_16x16x32_bf16(afrag[kt], bfrag, acc[jt], 0, 0, 0);
    }
  }

  if (o0 < 1024) {  // Q or K -> [b][h][n][d]
    short* dst = (o0 < 512) ? Qt : Kt;
    int oo = (o0 < 512) ? o0 : o0 - 512;
    int h = oo >> 7, d0 = (oo & 127) + l4 * 4;
    for (int jt = 0; jt < 8; ++jt) {
      int n = n0 + jt * 16 + l15;
      bf16x4 v4;
      for (int r = 0; r < 4; ++r) v4[r] = f2bf(acc[jt][r]);
      *(bf16x4*)(dst + (((size_t)b * NH + h) * HWN + n) * CD + d0) = v4;
    }
  } else {          // V -> [b][h][d][m] (+bv), scattered 2B stores
    int oo = o0 - 1024;
    int h = oo >> 7, d0 = (oo & 127) + l4 * 4;
    float bvv[4];
    for (int r = 0; r < 4; ++r) bvv[r] = bv[oo + l4 * 4 + r];
    for (int jt = 0; jt < 8; ++jt) {
      int n = n0 + jt * 16 + l15;
      for (int r = 0; r < 4; ++r)
        Vd[(((size_t)b * NH + h) * CD + d0 + r) * HWN + n] = f2bf(acc[jt][r] + bvv[r]);
    }
  }
}

// ---- flash attention per (b,h): S=1024, D=128 ---------------------------
// R3-proven structure + two validated fixes:
//  * 4 waves/block, wave owns 32 Q-rows (2 fragments), KVB=64, 16 iters.
//  * XCD chunk swizzle (grid 512): all 8 blocks of a (b,h) on one XCD's L2
//    (proven FETCH 139->~30 MB in R4/R5/R6).
//  * BOTH K and V staged block-cooperatively in LDS (double-buffered
//    global_load_lds width=16, XOR-swizzled via pre-swizzled global source).
//    V was previously read 4x-redundantly per block from global; staging
//    also frees the 64-VGPR V reg-buffer (R3: VGPR 100, no spills).
//  * Swapped QK^T -> in-register softmax (log2 domain, Q pre-scaled),
//    defer-max. P via per-wave LDS subtiles (single-buffered; compiler
//    orders intra-wave DS W->R by alias analysis).
//  * setprio(1) around MFMA clusters. LDS 80 KB -> 2 blocks/CU, grid 512.
__launch_bounds__(256, 2)
__global__ void attn(const short* __restrict__ Qt, const short* __restrict__ Kt,
                     const short* __restrict__ Vd, short* __restrict__ Oscr) {
  // XCD chunk swizzle: nwg=512, 8 XCDs, 64 blocks per XCD chunk (bijective).
  int wid = blockIdx.x;
  int work = (wid & 7) * 64 + (wid >> 3);
  int xb = work & 7;          // q-block of 128 rows
  int h = (work >> 3) & 3;
  int b = work >> 5;

  int wave = threadIdx.x >> 6, lane = threadIdx.x & 63;
  int l15 = lane & 15, l4 = lane >> 4;
  int n0 = xb * 128 + wave * 32;
  size_t bh = (size_t)b * NH + h;
  const short* q = Qt + bh * HWN * CD;
  const short* k = Kt + bh * HWN * CD;
  const short* v = Vd + bh * CD * HWN;

  __shared__ short Kls[2][KVB * CD];       // 2 x 16 KB, rows XOR-swizzled (byte^=(row&7)<<4)
  __shared__ short Vls[2][CD * KVB];       // 2 x 16 KB, [d][m] rows XOR-swizzled likewise
  __shared__ short pl[4][2][2][4][16][8];  // [wave][qf][ks][g][n][e] 16 KB

  // Stage K tile (64 rows x 128 c) and V tile (128 d x 64 m) into LDS[buf].
  // 16 x 1KB insts each, spread over 4 waves. LDS dest linear; global source
  // pre-swizzled so LDS row r holds bytes [col ^ ((r&7)<<4)] (rule #21).
#define STAGE(buf, m0s)                                                         \
  for (int j = 0; j < 4; ++j) {                                                 \
    int ii = wave * 4 + j;                                                      \
    int krow = ii * 4 + l4;                                                     \
    int kcol = (l15 * 16) ^ ((krow & 7) << 4);                                  \
    const short* kgp = k + (size_t)((m0s) + krow) * CD + (kcol >> 1);           \
    __builtin_amdgcn_global_load_lds(                                           \
        (const __attribute__((address_space(1))) void*)kgp,                     \
        (__attribute__((address_space(3))) void*)&Kls[buf][ii * 512], 16, 0, 0);\
    int vrow = ii * 8 + (lane >> 3);                                            \
    int vcol = ((lane & 7) * 16) ^ ((vrow & 7) << 4);                           \
    const short* vgp = v + (size_t)vrow * HWN + (m0s) + (vcol >> 1);            \
    __builtin_amdgcn_global_load_lds(                                           \
        (const __attribute__((address_space(1))) void*)vgp,                     \
        (__attribute__((address_space(3))) void*)&Vls[buf][ii * 512], 16, 0, 0);\
  }

  bf16x8 bq[2][4];  // Q as B-fragment (col = n, k = c), pre-scaled
  for (int qf = 0; qf < 2; ++qf)
    for (int kt = 0; kt < 4; ++kt)
      bq[qf][kt] = *(const bf16x8*)(q + (size_t)(n0 + qf * 16 + l15) * CD + kt * 32 + l4 * 8);

  f32x4 oacc[2][8];
  for (int qf = 0; qf < 2; ++qf)
    for (int jt = 0; jt < 8; ++jt) oacc[qf][jt] = (f32x4){0.f, 0.f, 0.f, 0.f};
  float mi[2] = {-1e30f, -1e30f}, li[2] = {0.f, 0.f};

  STAGE(0, 0)
  __syncthreads();

  for (int mt = 0; mt < 16; ++mt) {
    int m0 = mt * KVB;
    int cur = mt & 1;
    if (mt < 15) STAGE(cur ^ 1, m0 + KVB)

    // QK^T swapped: s[qf][t] = S^T[m0+16t+4*l4+r][n0+16qf+l15]; K from LDS (swizzled read)
    f32x4 s[2][4];
    for (int qf = 0; qf < 2; ++qf)
      for (int t = 0; t < 4; ++t) s[qf][t] = (f32x4){0.f, 0.f, 0.f, 0.f};
    __builtin_amdgcn_s_setprio(1);
#pragma unroll
    for (int t = 0; t < 4; ++t) {
      int row = t * 16 + l15;
#pragma unroll
      for (int kt = 0; kt < 4; ++kt) {
        bf16x8 ak = *(const bf16x8*)&Kls[cur][row * CD + ((kt * 32 + l4 * 8) ^ ((l15 & 7) << 3))];
        s[0][t] = __builtin_amdgcn_mfma_f32_16x16x32_bf16(ak, bq[0][kt], s[0][t], 0, 0, 0);
        s[1][t] = __builtin_amdgcn_mfma_f32_16x16x32_bf16(ak, bq[1][kt], s[1][t], 0, 0, 0);
      }
    }
    __builtin_amdgcn_s_setprio(0);

    // softmax stats: lane holds 16 of 64 m-values per q-row n=16qf+l15 (log2 domain)
    float mx[2];
    for (int qf = 0; qf < 2; ++qf) {
      float m2 = -1e30f;
      for (int t = 0; t < 4; ++t)
        for (int r = 0; r < 4; ++r) m2 = fmaxf(m2, s[qf][t][r]);
      m2 = fmaxf(m2, __shfl_xor(m2, 16));
      m2 = fmaxf(m2, __shfl_xor(m2, 32));
      mx[qf] = m2;
    }
    if (!__all((mx[0] - mi[0] <= 8.0f) && (mx[1] - mi[1] <= 8.0f))) {
      for (int qf = 0; qf < 2; ++qf) {
        float nm = fmaxf(mi[qf], mx[qf]);
        float fac = __builtin_amdgcn_exp2f(mi[qf] - nm);
        mi[qf] = nm;
        li[qf] *= fac;
        float facb[4];
        for (int r = 0; r < 4; ++r)
          facb[r] = __shfl(fac, (lane & 48) | (l4 * 4 + r));
        for (int jt = 0; jt < 8; ++jt)
          for (int r = 0; r < 4; ++r) oacc[qf][jt][r] *= facb[r];
      }
    }
    float p[2][4][4];
    for (int qf = 0; qf < 2; ++qf) {
      float ls = 0.f;
      for (int t = 0; t < 4; ++t)
        for (int r = 0; r < 4; ++r) {
          float e = __builtin_amdgcn_exp2f(s[qf][t][r] - mi[qf]);
          p[qf][t][r] = e;
          ls += e;
        }
      ls += __shfl_xor(ls, 16);
      ls += __shfl_xor(ls, 32);
      li[qf] += ls;
    }

    // P -> per-wave LDS subtiles, read back as A fragments
    for (int qf = 0; qf < 2; ++qf)
      for (int t = 0; t < 4; ++t) {
        bf16x4 c4;
        for (int r = 0; r < 4; ++r) c4[r] = f2bf(p[qf][t][r]);
        *(bf16x4*)&pl[wave][qf][t >> 1][2 * (t & 1) + (l4 >> 1)][l15][4 * (l4 & 1)] = c4;
      }
    bf16x8 ap[2][2];
    for (int qf = 0; qf < 2; ++qf)
      for (int ks = 0; ks < 2; ++ks)
        ap[qf][ks] = *(const bf16x8*)&pl[wave][qf][ks][l4][l15][0];

    // PV: V from LDS (swizzled read); 16 ds_read_b128 + 32 MFMA
    __builtin_amdgcn_s_setprio(1);
#pragma unroll
    for (int jt = 0; jt < 8; ++jt) {
      int d = jt * 16 + l15;
      const short* vb = &Vls[cur][d * KVB];
      bf16x8 bv0 = *(const bf16x8*)&vb[(l4 * 8) ^ ((d & 7) << 3)];
      bf16x8 bv1 = *(const bf16x8*)&vb[(32 + l4 * 8) ^ ((d & 7) << 3)];
      oacc[0][jt] = __builtin_amdgcn_mfma_f32_16x16x32_bf16(ap[0][0], bv0, oacc[0][jt], 0, 0, 0);
      oacc[1][jt] = __builtin_amdgcn_mfma_f32_16x16x32_bf16(ap[1][0], bv0, oacc[1][jt], 0, 0, 0);
      oacc[0][jt] = __builtin_amdgcn_mfma_f32_16x16x32_bf16(ap[0][1], bv1, oacc[0][jt], 0, 0, 0);
      oacc[1][jt] = __builtin_amdgcn_mfma_f32_16x16x32_bf16(ap[1][1], bv1, oacc[1][jt], 0, 0, 0);
    }
    __builtin_amdgcn_s_setprio(0);

    __syncthreads();  // staging for mt+1 complete; all waves done with K/V[cur]
  }
#undef STAGE

  // epilogue: O[n][d]/l -> Oscr[b][m=(n%8)*128+d][o=h*128+n/8]  (bijective)
  for (int qf = 0; qf < 2; ++qf) {
    float inv = 1.0f / li[qf];  // for row n = n0+16qf+l15, replicated over l4
    float invb[4];
    for (int r = 0; r < 4; ++r)
      invb[r] = __shfl(inv, (lane & 48) | (l4 * 4 + r));
    for (int jt = 0; jt < 8; ++jt) {
      int d = jt * 16 + l15;
      for (int r = 0; r < 4; ++r) {
        int n = n0 + qf * 16 + l4 * 4 + r;
        int o = h * CD + (n >> 3);
        int msp = (n & 7) * CD + d;
        Oscr[((size_t)b * HWN + msp) * 512 + o] = f2bf(oacc[qf][jt][r] * invb[r]);
      }
    }
  }
}

// ---- proj: out[b][c][m] = x + bt[c] + sum_o Wt[c][o]*OscrT[m][o] --------
__launch_bounds__(256)
__global__ void proj_kernel(const short* __restrict__ Oscr, const short* __restrict__ wtb,
                            const float* __restrict__ bt, const float* __restrict__ x,
                            float* __restrict__ out) {
  int b = blockIdx.y;
  int wave = threadIdx.x >> 6, lane = threadIdx.x & 63;
  int l15 = lane & 15, l4 = lane >> 4;
  int m0 = blockIdx.x * 64 + wave * 16;   // gridDim.x = 16

  f32x4 acc[8];
  for (int jt = 0; jt < 8; ++jt) acc[jt] = (f32x4){0.f, 0.f, 0.f, 0.f};

  const short* ob = Oscr + (size_t)b * HWN * 512;
  for (int kt = 0; kt < 16; ++kt) {
    bf16x8 a = *(const bf16x8*)(ob + (size_t)(m0 + l15) * 512 + kt * 32 + l4 * 8);
    for (int jt = 0; jt < 8; ++jt) {
      bf16x8 bw = *(const bf16x8*)(wtb + (size_t)(jt * 16 + l15) * 512 + kt * 32 + l4 * 8);
      acc[jt] = __builtin_amdgcn_mfma_f32_16x16x32_bf16(a, bw, acc[jt], 0, 0, 0);
    }
  }
  for (int jt = 0; jt < 8; ++jt) {
    int c = jt * 16 + l15;
    float btc = bt[c];
    size_t base = ((size_t)b * CD + c) * HWN + m0 + l4 * 4;
    f32x4 xr = *(const f32x4*)(x + base);
    f32x4 o;
    for (int r = 0; r < 4; ++r) o[r] = acc[jt][r] + xr[r] + btc;
    *(f32x4*)(out + base) = o;
  }
}

extern "C" void kernel_launch(void* const* d_in, const int* in_sizes, int n_in,
                              void* d_out, int out_size, void* d_ws, size_t ws_size,
                              hipStream_t stream) {
  const float* x  = (const float*)d_in[0];
  const float* Wq = (const float*)d_in[1];
  const float* Wk = (const float*)d_in[2];
  const float* Wv = (const float*)d_in[3];
  const float* bv = (const float*)d_in[4];
  const float* Wt = (const float*)d_in[5];
  const float* bt = (const float*)d_in[6];
  float* out = (float*)d_out;
  char* ws = (char*)d_ws;

  short* wqkv = (short*)(ws);
  short* wtb  = (short*)(ws + 393216);
  short* xt   = (short*)(ws + 524288);
  short* Qt   = (short*)(ws + 4718592);
  short* Kt   = (short*)(ws + 21495808);
  short* Vd   = (short*)(ws + 38273024);
  short* Oscr = (short*)(ws + 55050240);  // total 71827456 bytes

  hipLaunchKernelGGL(cvt_weights, dim3(256), dim3(256), 0, stream, Wq, Wk, Wv, Wt, wqkv, wtb);
  hipLaunchKernelGGL(cvt_transpose_x, dim3(32, 4, 16), dim3(256), 0, stream, x, xt);
  hipLaunchKernelGGL(qkv_gemm, dim3(8, 24, 16), dim3(256), 0, stream, wqkv, xt, bv, Qt, Kt, Vd);
  hipLaunchKernelGGL(attn, dim3(512), dim3(256), 0, stream, Qt, Kt, Vd, Oscr);
  hipLaunchKernelGGL(proj_kernel, dim3(16, 16), dim3(256), 0, stream, Oscr, wtb, bt, x, out);
}